// Round 4
// baseline (380.576 us; speedup 1.0000x reference)
//
#include <hip/hip_runtime.h>
#include <stdint.h>
#include <stddef.h>

typedef __fp16 f16;
typedef __attribute__((ext_vector_type(8))) __fp16 half8;
typedef __attribute__((ext_vector_type(4))) __fp16 half4;
typedef __attribute__((ext_vector_type(4))) float f32x4;

static __device__ __forceinline__ f32x4 mfma16(half8 a, half8 b, f32x4 c) {
    return __builtin_amdgcn_mfma_f32_16x16x32_f16(a, b, c, 0, 0, 0);
}
// raw HW transcendentals (1-ulp approx, plenty for f16 outputs)
static __device__ __forceinline__ float fexp2(float x) { float r; asm("v_exp_f32 %0, %1" : "=v"(r) : "v"(x)); return r; }
static __device__ __forceinline__ float frcp(float x)  { float r; asm("v_rcp_f32 %0, %1" : "=v"(r) : "v"(x)); return r; }

static constexpr float L2E  = 1.4426950408889634f;   // log2(e)
static constexpr float L2E2 = 2.8853900817779268f;   // 2*log2(e)

// LDS row strides (f16 elems): chosen so rows are 16B-aligned and
// b16 scatter-writes spread across banks (stride%32banks != 0)
static constexpr int LD256 = 280;   // 560B = 16*35, 140 banks = 12 mod 32
static constexpr int LD512 = 536;   // 1072B = 16*67, 268 banks = 12 mod 32

// ---------------- workspace layout (bytes) ----------------
static constexpr size_t OFF_EMB   = 0;                       // 50000*32*2 = 3,200,000
static constexpr size_t OFF_WQIH  = 3200000;                 // 128*32*2 (scaled)
static constexpr size_t OFF_WQHH  = OFF_WQIH + 8192;
static constexpr size_t OFF_WSIH  = OFF_WQHH + 8192;
static constexpr size_t OFF_WSHH  = OFF_WSIH + 8192;
static constexpr size_t OFF_BQ    = OFF_WSHH + 8192;         // 128*4 (scaled, f32)
static constexpr size_t OFF_BS    = OFF_BQ + 512;
static constexpr size_t OFF_G1WP  = OFF_BS + 512;            // 256*64*2
static constexpr size_t OFF_BIAS8 = OFF_G1WP + 32768;        // 8*256*4
static constexpr size_t OFF_G2W   = OFF_BIAS8 + 8192;        // 256*256*2
static constexpr size_t OFF_G3W   = OFF_G2W + 131072;
static constexpr size_t OFF_G4W   = OFF_G3W + 131072;
static constexpr size_t OFF_F1W   = OFF_G4W + 131072;
static constexpr size_t OFF_F2W   = OFF_F1W + 131072;        // 512*256*2
static constexpr size_t OFF_F3W   = OFF_F2W + 262144;        // 1000*512*2
static constexpr size_t OFF_HS    = OFF_F3W + 1024000;       // 32768*32*2
static constexpr size_t OFF_HQ    = OFF_HS + 2097152;        // 4096*32*2
static constexpr size_t OFF_ACT2  = OFF_HQ + 262144;         // 32768*256*2 = 16MB
static constexpr size_t WS_NEED   = OFF_ACT2 + 16777216;

// ---------------- fused fp32->fp16 conversion + small prep ----------------
struct CvtJobs { const float* src[7]; f16* dst[7]; int n[7]; };

__global__ __launch_bounds__(256) void cvt_prep(
    CvtJobs j,
    const float* __restrict__ g1W, const float* __restrict__ g1b,
    f16* __restrict__ wp, float* __restrict__ bias8,
    const float* __restrict__ qWih, const float* __restrict__ qWhh, const float* __restrict__ qb,
    const float* __restrict__ sWih, const float* __restrict__ sWhh, const float* __restrict__ sb,
    f16* __restrict__ wqih, f16* __restrict__ wqhh, float* __restrict__ bq,
    f16* __restrict__ wsih, f16* __restrict__ wshh, float* __restrict__ bs)
{
    int t = threadIdx.x;
    if (blockIdx.y < 7) {
        int jb = blockIdx.y;
        int i = (blockIdx.x * 256 + t) * 8;
        if (i >= j.n[jb]) return;
        const float* s = j.src[jb] + i;
        f32x4 a = *(const f32x4*)s;
        f32x4 b = *(const f32x4*)(s + 4);
        half8 o;
        o[0]=(f16)a[0]; o[1]=(f16)a[1]; o[2]=(f16)a[2]; o[3]=(f16)a[3];
        o[4]=(f16)b[0]; o[5]=(f16)b[1]; o[6]=(f16)b[2]; o[7]=(f16)b[3];
        *(half8*)(j.dst[jb] + i) = o;
        return;
    }
    // prep work
    if (blockIdx.x == 0) {
        int col = t;  // 0..255: g1 [256][65] -> [256][64] + bias8[8][256]
        for (int k = 0; k < 64; k++) wp[col * 64 + k] = (f16)g1W[col * 65 + k];
        float wpos = g1W[col * 65 + 64];
        float b = g1b[col];
        for (int i = 0; i < 8; i++) bias8[i * 256 + col] = b + (float)i * wpos;
    } else if (blockIdx.x == 1) {
        // LSTM prescale: rows i,f,o *(-log2e); g rows *(+2log2e)
        for (int i = t; i < 4096; i += 256) {
            int row = i >> 5;
            float s = (row < 64 || row >= 96) ? -L2E : L2E2;
            wqih[i] = (f16)(qWih[i] * s);
            wqhh[i] = (f16)(qWhh[i] * s);
            wsih[i] = (f16)(sWih[i] * s);
            wshh[i] = (f16)(sWhh[i] * s);
        }
        if (t < 128) {
            float s = (t < 64 || t >= 96) ? -L2E : L2E2;
            bq[t] = qb[t] * s;
            bs[t] = sb[t] * s;
        }
    }
}

// ---------------- fused LSTM, transposed-gate form ----------------
// One wave = 16 samples. sample = lane&15 for ALL operands.
// gates^T[128][16] = W * [x^T | h^T]; C layout: col=lane&15=sample,
// row = (lane>>4)*4 + r = gate row within 16-row tile n.
// Lane owns units u = jh*16 + kq*4 + r of its sample's h.
struct SfPtrs { const int* p[8]; };

__global__ __launch_bounds__(64) void lstm_kernel(
    SfPtrs sf, const int* __restrict__ qtok, const f16* __restrict__ emb_h,
    const f16* __restrict__ wih_sf, const f16* __restrict__ whh_sf, const float* __restrict__ b_sf,
    const f16* __restrict__ wih_q,  const f16* __restrict__ whh_q,  const float* __restrict__ b_q,
    f16* __restrict__ hs_out, f16* __restrict__ hq_out)
{
    __shared__ __align__(16) char hb[16 * 80];   // h[sample][unit], 80B row stride
    int lane = threadIdx.x;
    int c15 = lane & 15, kq = lane >> 4;
    int sbase = blockIdx.x * 16;
    bool isq = sbase >= 32768;
    const f16* wih = isq ? wih_q : wih_sf;
    const f16* whh = isq ? whh_q : whh_sf;
    const float* bvec = isq ? b_q : b_sf;

    // A-operand weight fragments: tile n = gate rows n*16..n*16+15
    // A[row=c15][k=kq*8+j] = W[n*16+c15][k]
    half8 wi[8], wh[8];
    f32x4 bc[8];
    #pragma unroll
    for (int n = 0; n < 8; n++) {
        wi[n] = *(const half8*)(wih + (n * 16 + c15) * 32 + kq * 8);
        wh[n] = *(const half8*)(whh + (n * 16 + c15) * 32 + kq * 8);
        bc[n] = *(const f32x4*)(bvec + n * 16 + kq * 4);   // bias for rows n*16+kq*4+r
    }
    // token pointer for this lane's sample
    int sg = sbase + c15;
    const int* tp;
    if (isq) tp = qtok + (sg - 32768) * 64;
    else     tp = sf.p[sg >> 12] + (sg & 4095) * 64;

    // zero h buffer (1280 B)
    f32x4 zro = {0.f, 0.f, 0.f, 0.f};
    *(f32x4*)(hb + lane * 16) = zro;
    if (lane < 16) *(f32x4*)(hb + 1024 + lane * 16) = zro;

    float cst[2][4] = {};
    const char* hrd = hb + c15 * 80 + kq * 16;   // h^T B-frag: units kq*8..+7 of sample c15

    int tok = tp[0];
    half8 xf = *(const half8*)(emb_h + (size_t)tok * 32 + kq * 8);   // x^T B-frag

    #pragma unroll 1
    for (int t = 0; t < 64; t++) {
        half8 hf = *(const half8*)hrd;
        f32x4 acc[8];
        #pragma unroll
        for (int n = 0; n < 8; n++) acc[n] = mfma16(wi[n], xf, bc[n]);
        #pragma unroll
        for (int n = 0; n < 8; n++) acc[n] = mfma16(wh[n], hf, acc[n]);
        if (t < 63) {
            int tk = tp[t + 1];
            xf = *(const half8*)(emb_h + (size_t)tk * 32 + kq * 8);
        }
        // acc_i/f/o hold -log2e*gate, acc_g holds +2log2e*gate (prescaled W,b)
        // ei=e^{-i}, ef=e^{-f}, eo=e^{-o}, eg=e^{2g}
        // c' = [c*t1*(eg+1) + (eg-1)*t2] / [t2*t1*(eg+1)]   (t1=1+ei,t2=1+ef)
        // h  = (ec-1) / [(ec+1)*(1+eo)],  ec=e^{2c'}
        #pragma unroll
        for (int jh = 0; jh < 2; jh++) {
            half4 hp;
            #pragma unroll
            for (int r = 0; r < 4; r++) {
                float ei = fexp2(acc[0 + jh][r]);
                float ef = fexp2(acc[2 + jh][r]);
                float eg = fexp2(acc[4 + jh][r]);
                float eo = fexp2(acc[6 + jh][r]);
                float t1 = 1.f + ei, t2 = 1.f + ef, t5 = 1.f + eo;
                float eg1 = eg + 1.f, egm = eg - 1.f;
                float num = fmaf(egm, t2, cst[jh][r] * t1 * eg1);
                float den = (t2 * t1) * eg1;
                float cn  = num * frcp(den);
                cst[jh][r] = cn;
                float ec  = fexp2(cn * L2E2);
                float hv  = (ec - 1.f) * frcp((ec + 1.f) * t5);
                hp[r] = (f16)hv;
            }
            // units jh*16+kq*4+0..3 of sample c15 -> bytes jh*32+kq*8..+8
            *(half4*)(hb + c15 * 80 + jh * 32 + kq * 8) = hp;
        }
        // DS ops are in-order within a wave; compiler inserts lgkmcnt for hf use.
    }
    // final h: lane reads its B-frag (16B) and stores contiguous
    half8 hv = *(const half8*)hrd;
    if (isq) *(half8*)(hq_out + (size_t)(sg - 32768) * 32 + kq * 8) = hv;
    else     *(half8*)(hs_out + (size_t)sg * 32 + kq * 8) = hv;
}

// ---------------- fused g1+g2+g3+g4 (one 32-row strip per block) ----------------
template<bool TOGLOBAL>
static __device__ __forceinline__ void layer256(
    const f16 (* __restrict__ src)[LD256], f16 (* __restrict__ dst)[LD256],
    const f16* __restrict__ W, const float* __restrict__ bias,
    f16* __restrict__ gout, int m0, int wv, int c15, int kq)
{
    f32x4 acc[2][4];
    #pragma unroll
    for (int a = 0; a < 2; a++)
        #pragma unroll
        for (int b = 0; b < 4; b++) acc[a][b] = (f32x4){0.f, 0.f, 0.f, 0.f};
    #pragma unroll
    for (int k0 = 0; k0 < 8; k0++) {
        half8 av[2], bv[4];
        #pragma unroll
        for (int fm = 0; fm < 2; fm++) av[fm] = *(const half8*)(&src[fm * 16 + c15][k0 * 32 + kq * 8]);
        #pragma unroll
        for (int fn = 0; fn < 4; fn++) bv[fn] = *(const half8*)(W + (size_t)(wv * 64 + fn * 16 + c15) * 256 + k0 * 32 + kq * 8);
        #pragma unroll
        for (int fm = 0; fm < 2; fm++)
            #pragma unroll
            for (int fn = 0; fn < 4; fn++) acc[fm][fn] = mfma16(av[fm], bv[fn], acc[fm][fn]);
    }
    #pragma unroll
    for (int fn = 0; fn < 4; fn++) {
        int col = wv * 64 + fn * 16 + c15;
        float bb = bias[col];
        #pragma unroll
        for (int fm = 0; fm < 2; fm++)
            #pragma unroll
            for (int r = 0; r < 4; r++) {
                float v = fmaxf(acc[fm][fn][r] + bb, 0.f);
                if (TOGLOBAL) gout[(size_t)(m0 + fm * 16 + kq * 4 + r) * 256 + col] = (f16)v;
                else          dst[fm * 16 + kq * 4 + r][col] = (f16)v;
            }
    }
}

__global__ __launch_bounds__(256) void gemm_g1234(
    const f16* __restrict__ hs, const f16* __restrict__ hq,
    const f16* __restrict__ g1wp, const float* __restrict__ bias8,
    const f16* __restrict__ g2w, const float* __restrict__ g2b,
    const f16* __restrict__ g3w, const float* __restrict__ g3b,
    const f16* __restrict__ g4w, const float* __restrict__ g4b,
    f16* __restrict__ act2)
{
    __shared__ __align__(16) f16 actA[32][LD256];
    __shared__ __align__(16) f16 actB[32][LD256];
    const int wv = threadIdx.x >> 6, lane = threadIdx.x & 63;
    const int c15 = lane & 15, kq = lane >> 4;
    const int m0 = blockIdx.x * 32;
    const float* brow = bias8 + ((m0 >> 12) << 8);

    { // g1: K=64 (hs || hq), bias8[rel] includes pos*w
        f32x4 acc[2][4];
        #pragma unroll
        for (int a = 0; a < 2; a++)
            #pragma unroll
            for (int b = 0; b < 4; b++) acc[a][b] = (f32x4){0.f, 0.f, 0.f, 0.f};
        half8 av[2], bv[4];
        #pragma unroll
        for (int fm = 0; fm < 2; fm++) av[fm] = *(const half8*)(hs + (size_t)(m0 + fm * 16 + c15) * 32 + kq * 8);
        #pragma unroll
        for (int fn = 0; fn < 4; fn++) bv[fn] = *(const half8*)(g1wp + (size_t)(wv * 64 + fn * 16 + c15) * 64 + kq * 8);
        #pragma unroll
        for (int fm = 0; fm < 2; fm++)
            #pragma unroll
            for (int fn = 0; fn < 4; fn++) acc[fm][fn] = mfma16(av[fm], bv[fn], acc[fm][fn]);
        #pragma unroll
        for (int fm = 0; fm < 2; fm++) av[fm] = *(const half8*)(hq + (size_t)((m0 + fm * 16 + c15) & 4095) * 32 + kq * 8);
        #pragma unroll
        for (int fn = 0; fn < 4; fn++) bv[fn] = *(const half8*)(g1wp + (size_t)(wv * 64 + fn * 16 + c15) * 64 + 32 + kq * 8);
        #pragma unroll
        for (int fm = 0; fm < 2; fm++)
            #pragma unroll
            for (int fn = 0; fn < 4; fn++) acc[fm][fn] = mfma16(av[fm], bv[fn], acc[fm][fn]);
        #pragma unroll
        for (int fn = 0; fn < 4; fn++) {
            int col = wv * 64 + fn * 16 + c15;
            float bb = brow[col];
            #pragma unroll
            for (int fm = 0; fm < 2; fm++)
                #pragma unroll
                for (int r = 0; r < 4; r++)
                    actA[fm * 16 + kq * 4 + r][col] = (f16)fmaxf(acc[fm][fn][r] + bb, 0.f);
        }
    }
    __syncthreads();
    layer256<false>(actA, actB, g2w, g2b, nullptr, m0, wv, c15, kq);
    __syncthreads();
    layer256<false>(actB, actA, g3w, g3b, nullptr, m0, wv, c15, kq);
    __syncthreads();
    layer256<true>(actA, actB, g4w, g4b, act2, m0, wv, c15, kq);
}

// ---------------- fused sum8 + f1 + f2 + f3 (one 16-row strip per block) ----------------
__global__ __launch_bounds__(256) void f123s_kernel(
    const f16* __restrict__ act2,
    const f16* __restrict__ f1w, const float* __restrict__ f1b,
    const f16* __restrict__ f2w, const float* __restrict__ f2b,
    const f16* __restrict__ f3w, const float* __restrict__ f3b,
    float* __restrict__ out)
{
    __shared__ __align__(16) f16 smbuf[16][LD256];
    __shared__ __align__(16) f16 f1buf[16][LD256];
    __shared__ __align__(16) f16 f2buf[16][LD512];
    const int b0 = blockIdx.x * 16;

    { // segment-sum over 8 relations, cooperative: thread t -> row t>>4, 16 cols
        int r = threadIdx.x >> 4, cb = (threadIdx.x & 15) * 16;
        float s[16] = {};
        #pragma unroll
        for (int i = 0; i < 8; i++) {
            const f16* p = act2 + ((size_t)(i * 4096 + b0 + r)) * 256 + cb;
            half8 v0 = *(const half8*)p;
            half8 v1 = *(const half8*)(p + 8);
            #pragma unroll
            for (int q = 0; q < 8; q++) { s[q] += (float)v0[q]; s[8 + q] += (float)v1[q]; }
        }
        half8 o0, o1;
        #pragma unroll
        for (int q = 0; q < 8; q++) { o0[q] = (f16)s[q]; o1[q] = (f16)s[8 + q]; }
        *(half8*)(&smbuf[r][cb]) = o0;
        *(half8*)(&smbuf[r][cb + 8]) = o1;
    }
    __syncthreads();
    const int wv = threadIdx.x >> 6, lane = threadIdx.x & 63;
    const int c15 = lane & 15, kq = lane >> 4;

    { // f1: [16x256] @ [256x256]^T, relu -> f1buf
        f32x4 acc[4];
        #pragma unroll
        for (int b = 0; b < 4; b++) acc[b] = (f32x4){0.f, 0.f, 0.f, 0.f};
        #pragma unroll
        for (int k0 = 0; k0 < 8; k0++) {
            half8 a = *(const half8*)(&smbuf[c15][k0 * 32 + kq * 8]);
            #pragma unroll
            for (int fn = 0; fn < 4; fn++) {
                half8 bv = *(const half8*)(f1w + (size_t)(wv * 64 + fn * 16 + c15) * 256 + k0 * 32 + kq * 8);
                acc[fn] = mfma16(a, bv, acc[fn]);
            }
        }
        #pragma unroll
        for (int fn = 0; fn < 4; fn++) {
            int col = wv * 64 + fn * 16 + c15;
            float bb = f1b[col];
            #pragma unroll
            for (int r = 0; r < 4; r++)
                f1buf[kq * 4 + r][col] = (f16)fmaxf(acc[fn][r] + bb, 0.f);
        }
    }
    __syncthreads();
    { // f2: [16x256] @ [512x256]^T, relu -> f2buf
        f32x4 acc[8];
        #pragma unroll
        for (int b = 0; b < 8; b++) acc[b] = (f32x4){0.f, 0.f, 0.f, 0.f};
        #pragma unroll
        for (int k0 = 0; k0 < 8; k0++) {
            half8 a = *(const half8*)(&f1buf[c15][k0 * 32 + kq * 8]);
            #pragma unroll
            for (int fn = 0; fn < 8; fn++) {
                half8 bv = *(const half8*)(f2w + (size_t)(wv * 128 + fn * 16 + c15) * 256 + k0 * 32 + kq * 8);
                acc[fn] = mfma16(a, bv, acc[fn]);
            }
        }
        #pragma unroll
        for (int fn = 0; fn < 8; fn++) {
            int col = wv * 128 + fn * 16 + c15;
            float bb = f2b[col];
            #pragma unroll
            for (int r = 0; r < 4; r++)
                f2buf[kq * 4 + r][col] = (f16)fmaxf(acc[fn][r] + bb, 0.f);
        }
    }
    __syncthreads();
    { // f3: [16x512] @ [1000x512]^T + b -> out (f32)
        f32x4 acc[16];
        #pragma unroll
        for (int b = 0; b < 16; b++) acc[b] = (f32x4){0.f, 0.f, 0.f, 0.f};
        #pragma unroll
        for (int k0 = 0; k0 < 16; k0++) {
            half8 a = *(const half8*)(&f2buf[c15][k0 * 32 + kq * 8]);
            #pragma unroll
            for (int jj = 0; jj < 16; jj++) {
                int col = (wv + 4 * jj) * 16 + c15;
                int cl = col < 1000 ? col : 999;
                half8 bv = *(const half8*)(f3w + (size_t)cl * 512 + k0 * 32 + kq * 8);
                acc[jj] = mfma16(a, bv, acc[jj]);
            }
        }
        #pragma unroll
        for (int jj = 0; jj < 16; jj++) {
            int col = (wv + 4 * jj) * 16 + c15;
            if (col < 1000) {
                float bb = f3b[col];
                #pragma unroll
                for (int r = 0; r < 4; r++)
                    out[(size_t)(b0 + kq * 4 + r) * 1000 + col] = acc[jj][r] + bb;
            }
        }
    }
}

// ---------------- launcher ----------------
extern "C" void kernel_launch(void* const* d_in, const int* in_sizes, int n_in,
                              void* d_out, int out_size, void* d_ws, size_t ws_size,
                              hipStream_t stream)
{
    if (ws_size < WS_NEED) return;
    const int* q_tok = (const int*)d_in[0];
    SfPtrs sf;
    for (int i = 0; i < 8; i++) sf.p[i] = (const int*)d_in[1 + i];
    const float* emb_f = (const float*)d_in[9];
    const float* qWih = (const float*)d_in[10];
    const float* qWhh = (const float*)d_in[11];
    const float* q_b  = (const float*)d_in[12];
    const float* sWih = (const float*)d_in[13];
    const float* sWhh = (const float*)d_in[14];
    const float* s_b  = (const float*)d_in[15];
    const float* g1W  = (const float*)d_in[16];
    const float* g1b  = (const float*)d_in[17];
    const float* g2W  = (const float*)d_in[18];
    const float* g2b  = (const float*)d_in[19];
    const float* g3W  = (const float*)d_in[20];
    const float* g3b  = (const float*)d_in[21];
    const float* g4W  = (const float*)d_in[22];
    const float* g4b  = (const float*)d_in[23];
    const float* f1W  = (const float*)d_in[24];
    const float* f1b  = (const float*)d_in[25];
    const float* f2W  = (const float*)d_in[26];
    const float* f2b  = (const float*)d_in[27];
    const float* f3W  = (const float*)d_in[28];
    const float* f3b  = (const float*)d_in[29];

    char* ws = (char*)d_ws;
    f16* emb_h = (f16*)(ws + OFF_EMB);
    f16* wqih  = (f16*)(ws + OFF_WQIH);
    f16* wqhh  = (f16*)(ws + OFF_WQHH);
    f16* wsih  = (f16*)(ws + OFF_WSIH);
    f16* wshh  = (f16*)(ws + OFF_WSHH);
    float* bq  = (float*)(ws + OFF_BQ);
    float* bs  = (float*)(ws + OFF_BS);
    f16* g1wp  = (f16*)(ws + OFF_G1WP);
    float* bias8 = (float*)(ws + OFF_BIAS8);
    f16* g2w = (f16*)(ws + OFF_G2W);
    f16* g3w = (f16*)(ws + OFF_G3W);
    f16* g4w = (f16*)(ws + OFF_G4W);
    f16* f1w = (f16*)(ws + OFF_F1W);
    f16* f2w = (f16*)(ws + OFF_F2W);
    f16* f3w = (f16*)(ws + OFF_F3W);
    f16* hs  = (f16*)(ws + OFF_HS);
    f16* hq  = (f16*)(ws + OFF_HQ);
    f16* act2 = (f16*)(ws + OFF_ACT2);

    CvtJobs cj;
    const float* srcs[7] = {emb_f, g2W, g3W, g4W, f1W, f2W, f3W};
    f16* dsts[7]         = {emb_h, g2w, g3w, g4w, f1w, f2w, f3w};
    int ns[7] = {1600000, 65536, 65536, 65536, 65536, 131072, 512000};
    for (int i = 0; i < 7; i++) { cj.src[i] = srcs[i]; cj.dst[i] = dsts[i]; cj.n[i] = ns[i]; }

    cvt_prep<<<dim3(782, 8), 256, 0, stream>>>(cj, g1W, g1b, g1wp, bias8,
                                               qWih, qWhh, q_b, sWih, sWhh, s_b,
                                               wqih, wqhh, bq, wsih, wshh, bs);
    lstm_kernel<<<2304, 64, 0, stream>>>(sf, q_tok, emb_h, wsih, wshh, bs, wqih, wqhh, bq, hs, hq);
    gemm_g1234<<<1024, 256, 0, stream>>>(hs, hq, g1wp, bias8, g2w, g2b, g3w, g3b, g4w, g4b, act2);
    f123s_kernel<<<256, 256, 0, stream>>>(act2, f1w, f1b, f2w, f2b, f3w, f3b, (float*)d_out);
}